// Round 11
// baseline (680.504 us; speedup 1.0000x reference)
//
#include <hip/hip_runtime.h>

#define HH  50    // hidden size
#define RB  16    // batch elements per block (= MFMA N)
#define TT  512   // timesteps
#define FF  4     // input features
#define PA  136   // hA row pitch in u16 (K'=128 + pad)
#define NCW 7     // compute waves; each owns TWO 16-row tiles (32 rows): 7*32=224 >= 200
#define NTH ((NCW + 1) * 64)   // 512: waves 0..6 compute, wave 7 streams x

typedef __attribute__((ext_vector_type(8))) short bf16x8;   // 8 bf16 = 4 VGPRs
typedef __attribute__((ext_vector_type(4))) float f32x4;    // MFMA accumulator

// fast sigmoid/tanh: v_exp + v_rcp (no fp32 divide expansion)
__device__ __forceinline__ float sigm(float x) {
    return __builtin_amdgcn_rcpf(1.0f + __expf(-x));
}
__device__ __forceinline__ float tanh_f(float x) {
    return fmaf(-2.0f, __builtin_amdgcn_rcpf(1.0f + __expf(2.0f * x)), 1.0f);
}

__device__ __forceinline__ unsigned short f2bf(float f) {   // RNE fp32->bf16 bits
    unsigned u = __float_as_uint(f);
    u += 0x7FFFu + ((u >> 16) & 1u);
    return (unsigned short)(u >> 16);
}
__device__ __forceinline__ float bf2f(unsigned short s) {
    return __uint_as_float(((unsigned)s) << 16);
}

// raw barrier: drains LDS ops (producer->consumer ordering) but NOT vmcnt --
// the x-writer wave's in-flight global prefetch stays in flight across it.
__device__ __forceinline__ void block_sync_lds() {
    asm volatile("s_waitcnt lgkmcnt(0)\n\ts_barrier" ::: "memory");
}

// split-bf16 W-frag (A operand) for K' elements kb+0..7. K-layout: k'<4 -> Wx,
// 4<=k'<54 -> Wm, else 0.
__device__ __forceinline__ void buildB(bf16x8& bh, bf16x8& bl,
    const float* Wx, const float* Wm, int row_o, bool rok, int kb) {
    #pragma unroll
    for (int ii = 0; ii < 8; ++ii) {
        const int k = kb + ii;
        float wv = 0.0f;
        if (rok) {
            if (k < FF) { if (Wx) wv = Wx[row_o * FF + k]; }
            else if (k < FF + HH) wv = Wm[row_o * HH + (k - FF)];
        }
        const unsigned short hb = f2bf(wv);
        bh[ii] = (short)hb;
        bl[ii] = (short)f2bf(wv - bf2f(hb));
    }
}

#define MFMA(a, b, c) __builtin_amdgcn_mfma_f32_16x16x32_bf16(a, b, c, 0, 0, 0)
#define PINB(V) asm volatile("" : "+v"(V));

// per-tile weight fragment set (12 frags = 48 VGPRs)
#define DECLB(S) bf16x8 B0h0##S, B0h1##S, B0l0##S, B0l1##S, \
                        B1h0##S, B1h1##S, B1l0##S, B1l1##S, \
                        B2h0##S, B2h1##S, B2l0##S, B2l1##S;
#define BUILDALL(S, ROWO, ROK) \
    buildB(B0h0##S, B0l0##S, Wih0, Whh0, ROWO, ROK, qk8); \
    buildB(B0h1##S, B0l1##S, Wih0, Whh0, ROWO, ROK, 32 + qk8); \
    buildB(B1h0##S, B1l0##S, nullptr, Wih1, ROWO, ROK, qk8); \
    buildB(B1h1##S, B1l1##S, nullptr, Wih1, ROWO, ROK, 32 + qk8); \
    buildB(B2h0##S, B2l0##S, nullptr, Whh1, ROWO, ROK, qk8); \
    buildB(B2h1##S, B2l1##S, nullptr, Whh1, ROWO, ROK, 32 + qk8);
#define PINALL(S) \
    PINB(B0h0##S) PINB(B0h1##S) PINB(B0l0##S) PINB(B0l1##S) \
    PINB(B1h0##S) PINB(B1h1##S) PINB(B1l0##S) PINB(B1l1##S) \
    PINB(B2h0##S) PINB(B2h1##S) PINB(B2l0##S) PINB(B2l1##S)

// elementwise + h-writeback for one unit (acc regs = gates i,f,g,o of unit UU, batch m)
#define EWL0(A1_, A2_, UU, UVAL, CS) if (UVAL) { \
    const float gi = sigm(A1_[0] + A2_[0]); \
    const float gf = sigm(A1_[1] + A2_[1]); \
    const float gc = tanh_f(A1_[2] + A2_[2]); \
    const float go = sigm(A1_[3] + A2_[3]); \
    CS = fmaf(gf, CS, gi * gc); \
    const float h = go * tanh_f(CS); \
    const unsigned short hb = f2bf(h); \
    hA0[wb][m * PA + 4 + (UU)]  = hb; \
    hA0[wb][m * PA + 68 + (UU)] = f2bf(h - bf2f(hb)); }
#define EWL1(A1_, A2_, UU, UVAL, CS) if (UVAL) { \
    const float gi = sigm(A1_[0] + A2_[0]); \
    const float gf = sigm(A1_[1] + A2_[1]); \
    const float gc = tanh_f(A1_[2] + A2_[2]); \
    const float go = sigm(A1_[3] + A2_[3]); \
    CS = fmaf(gf, CS, gi * gc); \
    const float h = go * tanh_f(CS); \
    const unsigned short hb = f2bf(h); \
    hA1[wb][m * PA + 4 + (UU)]  = hb; \
    hA1[wb][m * PA + 68 + (UU)] = f2bf(h - bf2f(hb)); \
    if (i == TT) h1f[(UU) * 16 + m] = h; }

__attribute__((amdgpu_waves_per_eu(2, 2)))
__launch_bounds__(NTH)
__global__ void lstm_v11(const float* __restrict__ x,
                         const float* __restrict__ Wih0, const float* __restrict__ Whh0,
                         const float* __restrict__ bih0, const float* __restrict__ bhh0,
                         const float* __restrict__ Wih1, const float* __restrict__ Whh1,
                         const float* __restrict__ bih1, const float* __restrict__ bhh1,
                         const float* __restrict__ fcW,  const float* __restrict__ fcb,
                         float* __restrict__ out)
{
    // ping-pong h buffers (split-bf16 B operands), K-layout [x(4) h_hi(50) .. | x_l(4) h_lo(50) ..]
    __shared__ __align__(16) unsigned short hA0[2][16 * PA];
    __shared__ __align__(16) unsigned short hA1[2][16 * PA];
    __shared__ float h1f[HH * 16];     // final h1 fp32 for FC

    const int tid  = threadIdx.x;
    const int w    = tid >> 6;
    const int lane = tid & 63;
    const int b0   = blockIdx.x * RB;

    const int n15 = lane & 15;
    const int qk  = lane >> 4;
    const int qk8 = qk * 8;

    // D = W . h^T: lane holds D[row'=qk*4+reg][batch=n15]; row' = 4*unit+gate
    // tile0 rows 32w..32w+15 -> unit u0 = 8w+qk; tile1 rows +16 -> u1 = 8w+4+qk
    const int m  = n15;
    const int u0 = w * 8 + qk;
    const int u1 = w * 8 + 4 + qk;
    const bool uv0 = (w < NCW) && (u0 < HH);
    const bool uv1 = (w < NCW) && (u1 < HH);
    const int um0 = uv0 ? u0 : 0;
    const int um1 = uv1 ? u1 : 0;

    // W-frag rows (A-operand M index) for the two tiles
    const int rowp0  = w * 32 + n15;
    const int rowp1  = w * 32 + 16 + n15;
    const int runit0 = rowp0 >> 2, runit1 = rowp1 >> 2;
    const bool rok0  = (w < NCW) && (runit0 < HH);
    const bool rok1  = (w < NCW) && (runit1 < HH);
    const int row_o0 = rok0 ? (rowp0 & 3) * HH + runit0 : 0;
    const int row_o1 = rok1 ? (rowp1 & 3) * HH + runit1 : 0;

    for (int idx = tid; idx < 16 * PA; idx += NTH) {
        hA0[0][idx] = 0; hA0[1][idx] = 0;
        hA1[0][idx] = 0; hA1[1][idx] = 0;
    }

    // ---- 24 register-resident split-bf16 W-frags (A operands), 2 tiles ----
    DECLB(_0) DECLB(_1)
    BUILDALL(_0, row_o0, rok0)
    BUILDALL(_1, row_o1, rok1)
    PINALL(_0) PINALL(_1)

    // biases preloaded into MFMA C operands (gates i,f,g,o of units u0 / u1)
    const f32x4 C0a = {bih0[0*HH + um0] + bhh0[0*HH + um0], bih0[1*HH + um0] + bhh0[1*HH + um0],
                       bih0[2*HH + um0] + bhh0[2*HH + um0], bih0[3*HH + um0] + bhh0[3*HH + um0]};
    const f32x4 C0b = {bih0[0*HH + um1] + bhh0[0*HH + um1], bih0[1*HH + um1] + bhh0[1*HH + um1],
                       bih0[2*HH + um1] + bhh0[2*HH + um1], bih0[3*HH + um1] + bhh0[3*HH + um1]};
    const f32x4 C1a = {bih1[0*HH + um0] + bhh1[0*HH + um0], bih1[1*HH + um0] + bhh1[1*HH + um0],
                       bih1[2*HH + um0] + bhh1[2*HH + um0], bih1[3*HH + um0] + bhh1[3*HH + um0]};
    const f32x4 C1b = {bih1[0*HH + um1] + bhh1[0*HH + um1], bih1[1*HH + um1] + bhh1[1*HH + um1],
                       bih1[2*HH + um1] + bhh1[2*HH + um1], bih1[3*HH + um1] + bhh1[3*HH + um1]};

    // x-writer wave prefetch registers (vm never drains at the raw barrier)
    const int xm = lane >> 2, xk = lane & 3;
    float xcur = 0.f, xnxt = 0.f;
    if (w == NCW) {
        xcur = x[((size_t)(b0 + xm) * TT + 1) * FF + xk];
        xnxt = x[((size_t)(b0 + xm) * TT + 2) * FF + xk];
    }

    __syncthreads();

    // x(0) into parity-0 buffer
    if (w == 0) {
        const float xv = x[((size_t)(b0 + xm) * TT + 0) * FF + xk];
        const unsigned short hb = f2bf(xv);
        hA0[0][xm * PA + xk]      = hb;
        hA0[0][xm * PA + 64 + xk] = f2bf(xv - bf2f(hb));
    }
    __syncthreads();

    float c00 = 0.f, c01 = 0.f, c10 = 0.f, c11 = 0.f;

    // iter i: gates0(i) from [x(i),h0(i-1)]; gates1(i-1) from h0(i-1),h1(i-2). ONE barrier.
    for (int i = 0; i <= TT; ++i) {
        const int rb = i & 1, wb = (i + 1) & 1;

        if (w < NCW) {
            // A-frags read ONCE, reused by both row-tiles (the round-11 point)
            const int ab = n15 * PA + qk8;
            const bf16x8 A0 = *(const bf16x8*)&hA0[rb][ab];
            const bf16x8 A1 = *(const bf16x8*)&hA0[rb][ab + 32];
            const bf16x8 A2 = *(const bf16x8*)&hA0[rb][ab + 64];
            const bf16x8 A3 = *(const bf16x8*)&hA0[rb][ab + 96];
            const bf16x8 A4 = *(const bf16x8*)&hA1[rb][ab];
            const bf16x8 A5 = *(const bf16x8*)&hA1[rb][ab + 32];
            const bf16x8 A6 = *(const bf16x8*)&hA1[rb][ab + 64];
            const bf16x8 A7 = *(const bf16x8*)&hA1[rb][ab + 96];

            if (i < TT) {   // ---- layer 0: 4 independent 3-chains (2 tiles) ----
                f32x4 a = C0a, ax = {0.f,0.f,0.f,0.f};
                f32x4 b = C0b, bx = {0.f,0.f,0.f,0.f};
                a  = MFMA(B0h0_0, A0, a);  ax = MFMA(B0h1_0, A3, ax);
                b  = MFMA(B0h0_1, A0, b);  bx = MFMA(B0h1_1, A3, bx);
                a  = MFMA(B0h1_0, A1, a);  ax = MFMA(B0l0_0, A0, ax);
                b  = MFMA(B0h1_1, A1, b);  bx = MFMA(B0l0_1, A0, bx);
                a  = MFMA(B0h0_0, A2, a);  ax = MFMA(B0l1_0, A1, ax);
                b  = MFMA(B0h0_1, A2, b);  bx = MFMA(B0l1_1, A1, bx);
                EWL0(a, ax, u0, uv0, c00)
                EWL0(b, bx, u1, uv1, c01)
            }
            if (i >= 1) {   // ---- layer 1: 4 independent 6-chains (2 tiles x ih/hh) ----
                f32x4 p = C1a, q = {0.f,0.f,0.f,0.f};
                f32x4 r = C1b, s = {0.f,0.f,0.f,0.f};
                p = MFMA(B1h0_0, A0, p); q = MFMA(B2h0_0, A4, q);
                r = MFMA(B1h0_1, A0, r); s = MFMA(B2h0_1, A4, s);
                p = MFMA(B1h1_0, A1, p); q = MFMA(B2h1_0, A5, q);
                r = MFMA(B1h1_1, A1, r); s = MFMA(B2h1_1, A5, s);
                p = MFMA(B1h0_0, A2, p); q = MFMA(B2h0_0, A6, q);
                r = MFMA(B1h0_1, A2, r); s = MFMA(B2h0_1, A6, s);
                p = MFMA(B1h1_0, A3, p); q = MFMA(B2h1_0, A7, q);
                r = MFMA(B1h1_1, A3, r); s = MFMA(B2h1_1, A7, s);
                p = MFMA(B1l0_0, A0, p); q = MFMA(B2l0_0, A4, q);
                r = MFMA(B1l0_1, A0, r); s = MFMA(B2l0_1, A4, s);
                p = MFMA(B1l1_0, A1, p); q = MFMA(B2l1_0, A5, q);
                r = MFMA(B1l1_1, A1, r); s = MFMA(B2l1_1, A5, s);
                EWL1(p, q, u0, uv0, c10)
                EWL1(r, s, u1, uv1, c11)
            }
        } else {
            // x-writer: issue next prefetch FIRST, then publish x(i+1) to write buffer
            float xnew = 0.f;
            if (i + 3 < TT) xnew = x[((size_t)(b0 + xm) * TT + (i + 3)) * FF + xk];
            if (i + 1 < TT) {
                const unsigned short hb = f2bf(xcur);
                hA0[wb][xm * PA + xk]      = hb;
                hA0[wb][xm * PA + 64 + xk] = f2bf(xcur - bf2f(hb));
            }
            xcur = xnxt;
            xnxt = xnew;
        }
        block_sync_lds();
    }

    __syncthreads();

    // ---- final FC: out[b] = fcW @ h1(T-1) + fcb ----
    if (tid < RB * FF) {
        const int r = tid >> 2, ft = tid & 3;
        float s = fcb[ft];
        #pragma unroll
        for (int j = 0; j < HH; j++) s = fmaf(fcW[ft * HH + j], h1f[j * 16 + r], s);
        out[(size_t)(b0 + r) * FF + ft] = s;
    }
}

extern "C" void kernel_launch(void* const* d_in, const int* in_sizes, int n_in,
                              void* d_out, int out_size, void* d_ws, size_t ws_size,
                              hipStream_t stream) {
    const float* x    = (const float*)d_in[0];
    const float* Wih0 = (const float*)d_in[1];
    const float* Whh0 = (const float*)d_in[2];
    const float* bih0 = (const float*)d_in[3];
    const float* bhh0 = (const float*)d_in[4];
    const float* Wih1 = (const float*)d_in[5];
    const float* Whh1 = (const float*)d_in[6];
    const float* bih1 = (const float*)d_in[7];
    const float* bhh1 = (const float*)d_in[8];
    const float* fcW  = (const float*)d_in[9];
    const float* fcb  = (const float*)d_in[10];
    float* out = (float*)d_out;

    const int B = in_sizes[0] / (TT * FF);   // 4096
    lstm_v11<<<B / RB, NTH, 0, stream>>>(x, Wih0, Whh0, bih0, bhh0,
                                         Wih1, Whh1, bih1, bhh1, fcW, fcb, out);
}